// Round 2
// baseline (282.806 us; speedup 1.0000x reference)
//
#include <hip/hip_runtime.h>

// Problem constants
#define NXC 128
#define NYC 128
#define NZC 4
#define BC  8
#define TC  10

#define TSTRIDE 65536            // NZ*NX*NY
#define NTOT    5242880          // B*T*NZ*NX*NY
#define NQUAD   1310720          // NTOT/4
#define HALFQ   655360           // NQUAD/2

// native clang vector (required by __builtin_nontemporal_*)
typedef float vf4 __attribute__((ext_vector_type(4)));

// __launch_bounds__(256, 8): 8 waves/EU = 8 blocks/CU = 32 waves/CU.
// Forces VGPR <= 64 (was 68 -- 4 regs past the 64-VGPR occupancy cliff,
// capping HW occupancy at 16 waves/CU; measured OccupancyPercent 25.6).
__global__ __launch_bounds__(256, 8) void blackoil_kernel(
    const float* __restrict__ pressure,
    const float* __restrict__ perm,
    const float* __restrict__ Q,
    const float* __restrict__ Qw,
    const float* __restrict__ Time_,
    const float* __restrict__ Phi,
    const float* __restrict__ Swini,
    const float* __restrict__ wsat,
    float* __restrict__ out)
{
    const int gid = blockIdx.x * blockDim.x + threadIdx.x;   // 0..HALFQ-1 exact

    const float sini = Swini[0];

    // per-quad loaded state (2 independent quads => ~26 float4 loads in flight)
    int   base_[2];
    vf4 pc_[2], pxm_[2], pxp_[2];
    float pym_[2], pyp_[2];
    vf4 k0c_[2], k0m_[2], k0p_[2];
    float kym_[2], kyp_[2];
    vf4 kc_[2], sat_[2], pri_[2], qv_[2], qwv_[2], tv_[2], phv_[2];
    int   t_[2];

    // ---------------- load phase: issue everything ----------------
#pragma unroll
    for (int k = 0; k < 2; ++k) {
        const int gq   = gid + k * HALFQ;
        const int base = gq << 2;
        base_[k] = base;

        const int y = base & (NYC - 1);          // multiple of 4
        const int x = (base >> 7) & (NXC - 1);
        const int t = (base >> 16) % TC;
        t_[k] = t;

        const int xm  = (x > 0)        ? -NYC : 0;
        const int xp  = (x < NXC - 1)  ?  NYC : 0;
        const int ymo = (y > 0)        ? -1   : 0;
        const int ypo = (y < NYC - 4)  ?  4   : 3;

        pc_ [k] = *(const vf4*)(pressure + base);
        pxm_[k] = *(const vf4*)(pressure + base + xm);
        pxp_[k] = *(const vf4*)(pressure + base + xp);
        pym_[k] = pressure[base + ymo];
        pyp_[k] = pressure[base + ypo];

        const int i0 = base - t * TSTRIDE;       // perm slice at t=0
        k0c_[k] = *(const vf4*)(perm + i0);
        k0m_[k] = *(const vf4*)(perm + i0 + xm);
        k0p_[k] = *(const vf4*)(perm + i0 + xp);
        kym_[k] = perm[i0 + ymo];
        kyp_[k] = perm[i0 + ypo];

        kc_ [k] = *(const vf4*)(perm + base);
        sat_[k] = *(const vf4*)(wsat + base);
        // unconditional load from a safe address; select sini afterwards
        const int ip = base - ((t > 0) ? TSTRIDE : 0);
        pri_[k] = *(const vf4*)(wsat + ip);

        // nontemporal: keep pure-streaming arrays OUT of L2 (round-1 A/B:
        // removing nt left FETCH_SIZE identical but regressed 46->63 us --
        // the nt flag prevents L2 pollution that evicts the stencil arrays).
        qv_ [k] = __builtin_nontemporal_load((const vf4*)(Q     + base));
        qwv_[k] = __builtin_nontemporal_load((const vf4*)(Qw    + base));
        tv_ [k] = __builtin_nontemporal_load((const vf4*)(Time_ + base));
        phv_[k] = __builtin_nontemporal_load((const vf4*)(Phi   + base));
    }

    __builtin_amdgcn_sched_barrier(0);   // keep all loads issued before compute

    // mobility constants from siniuse
    const float S0 = (sini - 0.1f) * 1.25f;      // /(1-SWI-SWR)=0.8
    const float cw = S0 * S0;
    const float ct = cw + (1.0f - S0) * (1.0f - S0) * (1.0f / 2.75f);
    const float scale = 7.8125e-8f;              // dxf * 1e-5 = 1e-5/128
    const float DK = 32000.0f;                   // 500 (perm rescale) * 64 (0.5/h)

    // ---------------- compute + store phase ----------------
#pragma unroll
    for (int k = 0; k < 2; ++k) {
        const int base = base_[k];
        vf4 pri = pri_[k];
        if (t_[k] == 0) { pri = (vf4){sini, sini, sini, sini}; }

        const float ucA [4] = { pc_[k].x,  pc_[k].y,  pc_[k].z,  pc_[k].w  };
        const float uxmA[4] = { pxm_[k].x, pxm_[k].y, pxm_[k].z, pxm_[k].w };
        const float uxpA[4] = { pxp_[k].x, pxp_[k].y, pxp_[k].z, pxp_[k].w };
        const float uymA[4] = { pym_[k],   pc_[k].x,  pc_[k].y,  pc_[k].z  };
        const float uypA[4] = { pc_[k].y,  pc_[k].z,  pc_[k].w,  pyp_[k]   };

        const float k0mA[4] = { k0m_[k].x, k0m_[k].y, k0m_[k].z, k0m_[k].w };
        const float k0pA[4] = { k0p_[k].x, k0p_[k].y, k0p_[k].z, k0p_[k].w };
        const float kymA[4] = { kym_[k],   k0c_[k].x, k0c_[k].y, k0c_[k].z };
        const float kypA[4] = { k0c_[k].y, k0c_[k].z, k0c_[k].w, kyp_[k]   };

        const float kcA [4] = { kc_[k].x,  kc_[k].y,  kc_[k].z,  kc_[k].w  };
        const float saA [4] = { sat_[k].x, sat_[k].y, sat_[k].z, sat_[k].w };
        const float prA [4] = { pri.x,     pri.y,     pri.z,     pri.w     };
        const float qA  [4] = { qv_[k].x,  qv_[k].y,  qv_[k].z,  qv_[k].w  };
        const float qwA [4] = { qwv_[k].x, qwv_[k].y, qwv_[k].z, qwv_[k].w };
        const float tmA [4] = { tv_[k].x,  tv_[k].y,  tv_[k].z,  tv_[k].w  };
        const float phA [4] = { phv_[k].x, phv_[k].y, phv_[k].z, phv_[k].w };

        float pl[4], sl[4];
#pragma unroll
        for (int j = 0; j < 4; ++j) {
            const float uc   = ucA[j]  * 1000.0f;
            const float uxm2 = uxmA[j] * 1000.0f;
            const float uxp2 = uxpA[j] * 1000.0f;
            const float uym2 = uymA[j] * 1000.0f;
            const float uyp2 = uypA[j] * 1000.0f;

            const float dudx   = (uxp2 - uxm2) * 64.0f;
            const float dudy   = (uyp2 - uym2) * 64.0f;
            const float dduddx = (uxp2 - 2.0f * uc + uxm2) * 16384.0f;
            const float dduddy = (uyp2 - 2.0f * uc + uym2) * 16384.0f;

            const float dpx = (k0pA[j] - k0mA[j]) * DK;
            const float dpy = (kypA[j] - kymA[j]) * DK;
            const float g1  = dpx * dudx + dpy * dudy;
            const float lap = dduddx + dduddy;

            const float a   = 500.0f * kcA[j];
            const float dsw = fmaxf(saA[j] - prA[j], 0.001f);
            const float S   = (prA[j] - 0.1f) * 1.25f;
            const float Mw  = S * S;
            const float Mo  = (1.0f - S) * (1.0f - S) * (1.0f / 2.75f);
            const float a1  = (Mw + Mo) * a;
            const float a1w = Mw * a;

            pl[j] = scale * (qA[j] * 5000.0f + ct * g1 + a1 * lap);
            const float flux = cw * g1 + a1w * lap;
            sl[j] = scale * (phA[j] * (dsw / (tmA[j] * 6000.0f)) - (flux + qwA[j] * 5000.0f));
        }

        vf4 po = { pl[0], pl[1], pl[2], pl[3] };
        vf4 so = { sl[0], sl[1], sl[2], sl[3] };
        __builtin_nontemporal_store(po, (vf4*)(out + base));
        __builtin_nontemporal_store(so, (vf4*)(out + base + NTOT));
    }
}

extern "C" void kernel_launch(void* const* d_in, const int* in_sizes, int n_in,
                              void* d_out, int out_size, void* d_ws, size_t ws_size,
                              hipStream_t stream) {
    const float* pressure = (const float*)d_in[0];
    const float* perm     = (const float*)d_in[1];
    const float* Q        = (const float*)d_in[2];
    const float* Qw       = (const float*)d_in[3];
    const float* Time_    = (const float*)d_in[4];
    // d_in[5] = Pini (unused by the reference)
    const float* Phi      = (const float*)d_in[6];
    const float* Swini    = (const float*)d_in[7];
    const float* wsat     = (const float*)d_in[8];
    float* out = (float*)d_out;

    const int threads = 256;
    const int blocks  = HALFQ / threads;     // 2560
    blackoil_kernel<<<blocks, threads, 0, stream>>>(
        pressure, perm, Q, Qw, Time_, Phi, Swini, wsat, out);
}

// Round 3
// 191.973 us; speedup vs baseline: 1.4732x; 1.4732x over previous
//
#include <hip/hip_runtime.h>

// Problem constants
#define NXC 128
#define NYC 128
#define NZC 4
#define BC  8
#define TC  10

#define TSTRIDE 65536            // NZ*NX*NY
#define NTOT    5242880          // B*T*NZ*NX*NY

// One ELEMENT per thread (r0 used 2 quads/thread -> 26 load dests ~112 regs
// vs 68 VGPRs available: compiler serialized the "load phase" anyway, and
// occupancy was stuck at ~3 waves/EU. 16 scalar loads fit in ~32-40 VGPRs
// -> natural 7-8 waves/EU without any forced budget; r2 proved forcing the
// budget (launch_bounds 256,8) spills catastrophically).
__global__ __launch_bounds__(256) void blackoil_kernel(
    const float* __restrict__ pressure,
    const float* __restrict__ perm,
    const float* __restrict__ Q,
    const float* __restrict__ Qw,
    const float* __restrict__ Time_,
    const float* __restrict__ Phi,
    const float* __restrict__ Swini,
    const float* __restrict__ wsat,
    float* __restrict__ out)
{
    const int gid = blockIdx.x * blockDim.x + threadIdx.x;   // 0..NTOT-1 exact

    const float sini = Swini[0];

    const int y = gid & (NYC - 1);
    const int x = (gid >> 7) & (NXC - 1);
    const int t = (gid >> 16) % TC;

    // replicate-pad stencil offsets (match jnp.pad mode='edge')
    const int xm = (x > 0)       ? -NYC : 0;
    const int xp = (x < NXC - 1) ?  NYC : 0;
    const int ym = (y > 0)       ? -1   : 0;
    const int yp = (y < NYC - 1) ?  1   : 0;

    // pressure 5-point stencil (coalesced dword loads; neighbors hit L1)
    const float pc  = pressure[gid];
    const float pxm = pressure[gid + xm];
    const float pxp = pressure[gid + xp];
    const float pym = pressure[gid + ym];
    const float pyp = pressure[gid + yp];

    // perm at t=0 slice of the same batch (mobility-derivative fields use
    // channel 0 only, broadcast over T)
    const int i0 = gid - t * TSTRIDE;
    const float k0xm = perm[i0 + xm];
    const float k0xp = perm[i0 + xp];
    const float k0ym = perm[i0 + ym];
    const float k0yp = perm[i0 + yp];

    const float kc = perm[gid];
    const float sa = wsat[gid];
    // prior saturation: shifted wsat, or sini at t=0 (safe unconditional load)
    const float prload = wsat[gid - ((t > 0) ? TSTRIDE : 0)];

    // nontemporal: pure-streaming arrays stay OUT of L2 (r1 A/B: removing nt
    // left FETCH_SIZE identical but regressed 46->63 us via L2 pollution).
    const float q  = __builtin_nontemporal_load(Q     + gid);
    const float qw = __builtin_nontemporal_load(Qw    + gid);
    const float tm = __builtin_nontemporal_load(Time_ + gid);
    const float ph = __builtin_nontemporal_load(Phi   + gid);

    const float pr = (t == 0) ? sini : prload;

    // mobility constants from siniuse (t=0 prior sat is the constant sini)
    const float S0 = (sini - 0.1f) * 1.25f;      // /(1-SWI-SWR)=0.8
    const float cw = S0 * S0;
    const float ct = cw + (1.0f - S0) * (1.0f - S0) * (1.0f / 2.75f);
    const float scale = 7.8125e-8f;              // dxf * 1e-5 = 1e-5/128
    const float DK = 32000.0f;                   // 500 (perm rescale) * 64 (0.5/h)

    const float uc   = pc  * 1000.0f;
    const float uxm2 = pxm * 1000.0f;
    const float uxp2 = pxp * 1000.0f;
    const float uym2 = pym * 1000.0f;
    const float uyp2 = pyp * 1000.0f;

    const float dudx   = (uxp2 - uxm2) * 64.0f;
    const float dudy   = (uyp2 - uym2) * 64.0f;
    const float dduddx = (uxp2 - 2.0f * uc + uxm2) * 16384.0f;
    const float dduddy = (uyp2 - 2.0f * uc + uym2) * 16384.0f;

    const float dpx = (k0xp - k0xm) * DK;
    const float dpy = (k0yp - k0ym) * DK;
    const float g1  = dpx * dudx + dpy * dudy;
    const float lap = dduddx + dduddy;

    const float a   = 500.0f * kc;
    const float dsw = fmaxf(sa - pr, 0.001f);
    const float S   = (pr - 0.1f) * 1.25f;
    const float Mw  = S * S;
    const float Mo  = (1.0f - S) * (1.0f - S) * (1.0f / 2.75f);
    const float a1  = (Mw + Mo) * a;
    const float a1w = Mw * a;

    const float pl = scale * (q * 5000.0f + ct * g1 + a1 * lap);
    const float flux = cw * g1 + a1w * lap;
    const float sl = scale * (ph * (dsw / (tm * 6000.0f)) - (flux + qw * 5000.0f));

    __builtin_nontemporal_store(pl, out + gid);
    __builtin_nontemporal_store(sl, out + gid + NTOT);
}

extern "C" void kernel_launch(void* const* d_in, const int* in_sizes, int n_in,
                              void* d_out, int out_size, void* d_ws, size_t ws_size,
                              hipStream_t stream) {
    const float* pressure = (const float*)d_in[0];
    const float* perm     = (const float*)d_in[1];
    const float* Q        = (const float*)d_in[2];
    const float* Qw       = (const float*)d_in[3];
    const float* Time_    = (const float*)d_in[4];
    // d_in[5] = Pini (unused by the reference)
    const float* Phi      = (const float*)d_in[6];
    const float* Swini    = (const float*)d_in[7];
    const float* wsat     = (const float*)d_in[8];
    float* out = (float*)d_out;

    const int threads = 256;
    const int blocks  = NTOT / threads;      // 20480
    blackoil_kernel<<<blocks, threads, 0, stream>>>(
        pressure, perm, Q, Qw, Time_, Phi, Swini, wsat, out);
}